// Round 17
// baseline (167.680 us; speedup 1.0000x reference)
//
#include <hip/hip_runtime.h>

#define N_ 4096

typedef __attribute__((ext_vector_type(8))) short bf16x8;
typedef __attribute__((ext_vector_type(4))) short bf16x4;
typedef __attribute__((ext_vector_type(4))) float f32x4;
typedef __attribute__((ext_vector_type(4))) float float4v;

__device__ __forceinline__ float ssqrt(float a) {
  if (a == 0.f) return 0.f;
  return copysignf(sqrtf(fabsf(a) + 1e-5f), a);
}

__device__ __forceinline__ ushort f2bf(float f) {
  uint u = __float_as_uint(f);
  u += 0x7fff + ((u >> 16) & 1);  // RNE
  return (ushort)(u >> 16);
}
__device__ __forceinline__ float bf2f(ushort h) {
  return __uint_as_float((uint)h << 16);
}

// cheap truncation-based hi/lo split: hi+lo == f up to 2^-16 rel (lo truncated)
__device__ __forceinline__ void split2(float f, ushort& hi, ushort& lo) {
  uint u = __float_as_uint(f);
  hi = (ushort)(u >> 16);
  float lof = f - __uint_as_float(u & 0xffff0000u);
  lo = (ushort)(__float_as_uint(lof) >> 16);
}

__device__ __forceinline__ f32x4 mfma16(bf16x8 a, bf16x8 b, f32x4 c) {
  return __builtin_amdgcn_mfma_f32_16x16x32_bf16(a, b, c, 0, 0, 0);
}

// non-temporal float4 store (nt flag: bypass L2/L3 - data never re-read)
__device__ __forceinline__ void nt_store4(float* p, float x, float y, float z, float w) {
  f32x4 v = {x, y, z, w};
  __builtin_nontemporal_store(v, (f32x4*)p);
}
// non-temporal float4 load (data read exactly once - don't allocate in cache)
__device__ __forceinline__ f32x4 nt_load4(const float* p) {
  return __builtin_nontemporal_load((const f32x4*)p);
}

// packed relu on 8 bf16 (zero any half-word with sign bit set)
__device__ __forceinline__ bf16x8 relu8(bf16x8 v) {
  union { bf16x8 h; uint u[4]; } x;
  x.h = v;
#pragma unroll
  for (int i = 0; i < 4; ++i) {
    uint m = x.u[i] & 0x80008000u;
    x.u[i] &= ~((m >> 15) * 0xFFFFu);
  }
  return x.h;
}

// load 8 consecutive bf16 from an 8B-aligned LDS addr (2 x b64)
__device__ __forceinline__ bf16x8 ld8_b64(const ushort* p) {
  bf16x4 a = *(const bf16x4*)p;
  bf16x4 b = *(const bf16x4*)(p + 4);
  return (bf16x8){a[0], a[1], a[2], a[3], b[0], b[1], b[2], b[3]};
}

// ---------------- K1: Gram for stage 1 (MFMA bf16x3), 6 unique panel-pairs ----------------
__global__ __launch_bounds__(256) void k1_gram(const float* __restrict__ x,
    float* __restrict__ Gp, float* __restrict__ sums) {
  const int GQ[6] = {0, 0, 1, 1, 2, 2};
  const int GK[6] = {2, 3, 3, 4, 4, 5};
  int bid = (blockIdx.x & 7) * 48 + (blockIdx.x >> 3);
  int s = bid / 96, rem = bid % 96;
  int b = rem / 6, pid = rem % 6;
  int gq = GQ[pid], gk = GK[pid];
  const float* A = x + ((size_t)b * 512 + gq * 64) * N_ + s * 1024;
  const float* B = x + ((size_t)b * 512 + gk * 64) * N_ + s * 1024;
  __shared__ __attribute__((aligned(16))) ushort Ah[64][72], Al[64][72];
  __shared__ __attribute__((aligned(16))) ushort Bh[64][72], Bl[64][72];
  int t = threadIdx.x;
  int lr = t >> 2, lq = t & 3;
  int l = t & 63, w = t >> 6;
  int mw = (w >> 1) * 32, nw = (w & 1) * 32;
  int fr = l & 15, ko = (l >> 4) * 8;
  float sumA = 0.f, sumB = 0.f;
  f32x4 acc[2][2];
#pragma unroll
  for (int i = 0; i < 2; ++i)
#pragma unroll
    for (int j = 0; j < 2; ++j) acc[i][j] = (f32x4){0.f, 0.f, 0.f, 0.f};

  for (int kt = 0; kt < 16; ++kt) {
    int kbase = kt * 64 + lq * 16;
#pragma unroll
    for (int j = 0; j < 4; ++j) {
      float4 va = *(const float4*)(A + (size_t)lr * N_ + kbase + j * 4);
      float4 vb = *(const float4*)(B + (size_t)lr * N_ + kbase + j * 4);
      sumA += va.x + va.y + va.z + va.w;
      sumB += vb.x + vb.y + vb.z + vb.w;
      ushort4 ha, la, hb, lb;
      split2(va.x, ha.x, la.x); split2(va.y, ha.y, la.y);
      split2(va.z, ha.z, la.z); split2(va.w, ha.w, la.w);
      split2(vb.x, hb.x, lb.x); split2(vb.y, hb.y, lb.y);
      split2(vb.z, hb.z, lb.z); split2(vb.w, hb.w, lb.w);
      int c0 = lq * 16 + j * 4;
      *(ushort4*)&Ah[lr][c0] = ha;
      *(ushort4*)&Al[lr][c0] = la;
      *(ushort4*)&Bh[lr][c0] = hb;
      *(ushort4*)&Bl[lr][c0] = lb;
    }
    __syncthreads();
#pragma unroll
    for (int wk = 0; wk < 2; ++wk) {
      int kk = wk * 32 + ko;
      bf16x8 ah[2], al[2], bh[2], bl[2];
#pragma unroll
      for (int mt = 0; mt < 2; ++mt) {
        ah[mt] = *(const bf16x8*)&Ah[mw + mt * 16 + fr][kk];
        al[mt] = *(const bf16x8*)&Al[mw + mt * 16 + fr][kk];
      }
#pragma unroll
      for (int nt = 0; nt < 2; ++nt) {
        bh[nt] = *(const bf16x8*)&Bh[nw + nt * 16 + fr][kk];
        bl[nt] = *(const bf16x8*)&Bl[nw + nt * 16 + fr][kk];
      }
#pragma unroll
      for (int mt = 0; mt < 2; ++mt)
#pragma unroll
        for (int nt = 0; nt < 2; ++nt) {
          acc[mt][nt] = mfma16(ah[mt], bh[nt], acc[mt][nt]);
          acc[mt][nt] = mfma16(ah[mt], bl[nt], acc[mt][nt]);
          acc[mt][nt] = mfma16(al[mt], bh[nt], acc[mt][nt]);
        }
    }
    __syncthreads();
  }
  size_t base = ((size_t)s * 96 + rem) * 4096;
#pragma unroll
  for (int mt = 0; mt < 2; ++mt)
#pragma unroll
    for (int nt = 0; nt < 2; ++nt)
#pragma unroll
      for (int reg = 0; reg < 4; ++reg) {
        int gr = mw + mt * 16 + (l >> 4) * 4 + reg;
        int gc = nw + nt * 16 + fr;
        __builtin_nontemporal_store(acc[mt][nt][reg],
                                    &Gp[base + (size_t)gr * 64 + gc]);
      }
  sumA += __shfl_xor(sumA, 1); sumA += __shfl_xor(sumA, 2);
  sumB += __shfl_xor(sumB, 1); sumB += __shfl_xor(sumB, 2);
  if (lq == 0) {
    sums[(((size_t)s * 16 + b) * 6 + gq) * 64 + lr] = sumA;
    sums[(((size_t)s * 16 + b) * 6 + gk) * 64 + lr] = sumB;
  }
}

// ---------------- K2: per-(b,h) attention algebra ----------------
__global__ __launch_bounds__(256) void k2_attn1(
    const float* __restrict__ w1, const float* __restrict__ b1,
    const float* __restrict__ Gp, const float* __restrict__ sums,
    ushort* __restrict__ M1h, ushort* __restrict__ M1l,
    float* __restrict__ pbv1) {
  const int PID[8] = {0, 1, 1, 2, 3, 3, 4, 5};
  int bh = blockIdx.x;
  int b = bh >> 3, h = bh & 7;
  int pid = PID[h];
  int mq = h, mk = 8 + h, mv = 16 + h;
  int gq = mq / 3, oq0 = (mq % 3) * 64;
  int gk = mk / 3, ok0 = (mk % 3) * 64;
  int gv = mv / 3, ov0 = (mv % 3) * 64;
  __shared__ __attribute__((aligned(16))) float Gs[64][68];
  __shared__ __attribute__((aligned(16))) float Was[64][68];
  __shared__ __attribute__((aligned(16))) float Wbs[64][68];
  __shared__ __attribute__((aligned(16))) float Ts[64][68];
  __shared__ float sxs[64], sks[64], vqs[64], vks[64], bvs[64];
  int t = threadIdx.x, tx = t & 15, ty = t >> 4;
  int d0 = ty * 4, e0 = tx * 4;

  for (int f = t; f < 4096; f += 256) {
    int dd = f >> 6, ee = f & 63;
    float g = 0.f;
#pragma unroll
    for (int s = 0; s < 4; ++s)
      g += __builtin_nontemporal_load(
          &Gp[((size_t)s * 96 + b * 6 + pid) * 4096 + f]);
    Gs[dd][ee] = g;
    Was[dd][ee] = w1[((size_t)(gq * 192 + oq0 + dd)) * 64 + ee];
    Wbs[dd][ee] = w1[((size_t)(gk * 192 + ok0 + dd)) * 64 + ee];
  }
  if (t < 64) {
    float v = 0.f, w = 0.f;
#pragma unroll
    for (int s = 0; s < 4; ++s) {
      v += sums[(((size_t)s * 16 + b) * 6 + gq) * 64 + t];
      w += sums[(((size_t)s * 16 + b) * 6 + gk) * 64 + t];
    }
    sxs[t] = v; sks[t] = w;
    bvs[t] = b1[gv * 192 + ov0 + t];
  }
  __syncthreads();
  if (t < 64) {
    float vq = 0.f, vk = 0.f;
    for (int i = 0; i < 64; ++i) { vq += Was[t][i] * sxs[i]; vk += Wbs[t][i] * sks[i]; }
    vqs[t] = vq; vks[t] = vk;
  }
  {
    float acc[4][4] = {};
    for (int i = 0; i < 64; i += 4) {
      float4 a4[4], g4[4];
#pragma unroll
      for (int r = 0; r < 4; ++r) a4[r] = *(const float4*)&Was[d0 + r][i];
#pragma unroll
      for (int k = 0; k < 4; ++k) g4[k] = *(const float4*)&Gs[i + k][e0];
#pragma unroll
      for (int r = 0; r < 4; ++r) {
        const float* ap = (const float*)&a4[r];
#pragma unroll
        for (int k = 0; k < 4; ++k) {
          const float* gp = (const float*)&g4[k];
#pragma unroll
          for (int c = 0; c < 4; ++c) acc[r][c] += ap[k] * gp[c];
        }
      }
    }
#pragma unroll
    for (int r = 0; r < 4; ++r)
#pragma unroll
      for (int c = 0; c < 4; ++c) Ts[d0 + r][e0 + c] = acc[r][c];
  }
  __syncthreads();
  float P[4][4];
  {
    float s[4][4] = {};
    for (int j = 0; j < 64; j += 4) {
      float4 t4[4], w4[4];
#pragma unroll
      for (int r = 0; r < 4; ++r) t4[r] = *(const float4*)&Ts[d0 + r][j];
#pragma unroll
      for (int c = 0; c < 4; ++c) w4[c] = *(const float4*)&Wbs[e0 + c][j];
#pragma unroll
      for (int r = 0; r < 4; ++r)
#pragma unroll
        for (int c = 0; c < 4; ++c)
          s[r][c] += t4[r].x * w4[c].x + t4[r].y * w4[c].y
                   + t4[r].z * w4[c].z + t4[r].w * w4[c].w;
    }
    float bq_[4], bk_[4];
#pragma unroll
    for (int r = 0; r < 4; ++r) bq_[r] = b1[gq * 192 + oq0 + d0 + r];
#pragma unroll
    for (int c = 0; c < 4; ++c) bk_[c] = b1[gk * 192 + ok0 + e0 + c];
#pragma unroll
    for (int r = 0; r < 4; ++r)
#pragma unroll
      for (int c = 0; c < 4; ++c) {
        float v = (s[r][c] + bq_[r] * vks[e0 + c] + bk_[c] * vqs[d0 + r]
                   + 4096.f * bq_[r] * bk_[c]) * 0.125f;
        s[r][c] = ssqrt(v);
      }
#pragma unroll
    for (int r = 0; r < 4; ++r) {
      float m = fmaxf(fmaxf(s[r][0], s[r][1]), fmaxf(s[r][2], s[r][3]));
#pragma unroll
      for (int mm = 1; mm < 16; mm <<= 1) m = fmaxf(m, __shfl_xor(m, mm));
      float sum = 0.f;
#pragma unroll
      for (int c = 0; c < 4; ++c) { s[r][c] = expf(s[r][c] - m); sum += s[r][c]; }
#pragma unroll
      for (int mm = 1; mm < 16; mm <<= 1) sum += __shfl_xor(sum, mm);
      float inv = 1.f / sum;
#pragma unroll
      for (int c = 0; c < 4; ++c) P[r][c] = s[r][c] * inv;
    }
  }
#pragma unroll
  for (int r = 0; r < 4; ++r)
#pragma unroll
    for (int c = 0; c < 4; ++c) Gs[d0 + r][e0 + c] = P[r][c];
  for (int f = t; f < 4096; f += 256) {
    int ee = f >> 6, ii = f & 63;
    Was[ee][ii] = w1[((size_t)(gv * 192 + ov0 + ee)) * 64 + ii];
  }
  __syncthreads();
  {
    float acc[4][4] = {};
    for (int e = 0; e < 64; e += 4) {
      float4 p4[4], v4[4];
#pragma unroll
      for (int r = 0; r < 4; ++r) p4[r] = *(const float4*)&Gs[d0 + r][e];
#pragma unroll
      for (int k = 0; k < 4; ++k) v4[k] = *(const float4*)&Was[e + k][e0];
#pragma unroll
      for (int r = 0; r < 4; ++r) {
        const float* pp = (const float*)&p4[r];
#pragma unroll
        for (int k = 0; k < 4; ++k) {
          const float* vp = (const float*)&v4[k];
#pragma unroll
          for (int c = 0; c < 4; ++c) acc[r][c] += pp[k] * vp[c];
        }
      }
    }
    ushort* MoH = M1h + (size_t)bh * 4096;
    ushort* MoL = M1l + (size_t)bh * 4096;
#pragma unroll
    for (int r = 0; r < 4; ++r)
#pragma unroll
      for (int c = 0; c < 4; ++c) {
        float vv = acc[r][c];
        ushort hi = f2bf(vv);
        MoH[(size_t)(d0 + r) * 64 + e0 + c] = hi;
        MoL[(size_t)(d0 + r) * 64 + e0 + c] = f2bf(vv - bf2f(hi));
      }
  }
  if (t < 64) {
    float pb = 0.f;
    for (int e = 0; e < 64; ++e) pb += Gs[t][e] * bvs[e];
    pbv1[(size_t)bh * 64 + t] = pb;
  }
}

// ---------------- K3: outT = XvT @ M^T via MFMA; +pbv+res, BN, permute -> y (bf16) ----------------
// Xr is single-use (residual, x never read after k3) -> NT loads keep the
// multiply-reused Xv panels resident in L2.
__global__ __launch_bounds__(256) void k3_out1(const float* __restrict__ x,
    const ushort* __restrict__ M1h, const ushort* __restrict__ M1l,
    const float* __restrict__ pbv1,
    const float* __restrict__ gamma, const float* __restrict__ beta,
    const float* __restrict__ rmean, const float* __restrict__ rvar,
    ushort* __restrict__ y) {
  int orig = (blockIdx.x & 7) * 256 + (blockIdx.x >> 3);
  int b = orig >> 7;
  int rem = orig & 127;
  int chunk = rem >> 3, h = rem & 7;
  int bh = b * 8 + h;
  int gv = (16 + h) / 3;
  const float* Xv = x + ((size_t)b * 512 + gv * 64) * N_ + chunk * 256;
  const float* Xr = x + ((size_t)b * 512 + h * 64) * N_ + chunk * 256;
  ushort* Y = y + (size_t)b * 512 * N_ + chunk * 256;

  __shared__ __attribute__((aligned(16))) ushort Xth[64][68], Xtl[64][68];  // [n][e]
  __shared__ float pbs[64], invs[64], adds[64];
  int t = threadIdx.x;
  if (t < 64) {
    pbs[t] = pbv1[(size_t)bh * 64 + t];
    int c = t * 8 + h;
    float iv = gamma[c] / sqrtf(rvar[c] + 1e-5f);
    invs[t] = iv;
    adds[t] = beta[c] - rmean[c] * iv;
  }
  int l = t & 63, w = t >> 6;
  int dq = w >> 1, nq = w & 1;   // wave quadrant: 32d x 32n
  int fr = l & 15, g = l >> 4;

  bf16x8 mh[2][2], ml[2][2];  // [drep][wk]
  {
    const ushort* MbH = M1h + (size_t)bh * 4096;
    const ushort* MbL = M1l + (size_t)bh * 4096;
#pragma unroll
    for (int dr = 0; dr < 2; ++dr)
#pragma unroll
      for (int wk = 0; wk < 2; ++wk) {
        int off = (dq * 32 + dr * 16 + fr) * 64 + wk * 32 + g * 8;
        mh[dr][wk] = *(const bf16x8*)(MbH + off);
        ml[dr][wk] = *(const bf16x8*)(MbL + off);
      }
  }

  int e2 = t >> 3, q = t & 7;
  for (int tile = 0; tile < 4; ++tile) {
    int nb = tile * 64;
    {
      const float* r0p = Xv + (size_t)(2 * e2) * N_ + nb + q * 8;
      const float* r1p = r0p + N_;
      float4 a0 = *(const float4*)r0p, a1 = *(const float4*)(r0p + 4);
      float4 b0 = *(const float4*)r1p, b1 = *(const float4*)(r1p + 4);
      float ra[8] = {a0.x, a0.y, a0.z, a0.w, a1.x, a1.y, a1.z, a1.w};
      float rb[8] = {b0.x, b0.y, b0.z, b0.w, b1.x, b1.y, b1.z, b1.w};
#pragma unroll
      for (int i = 0; i < 8; ++i) {
        int n = q * 8 + i;
        ushort h0, l0, h1, l1;
        split2(ra[i], h0, l0);
        split2(rb[i], h1, l1);
        *(uint*)&Xth[n][2 * e2] = (uint)h0 | ((uint)h1 << 16);
        *(uint*)&Xtl[n][2 * e2] = (uint)l0 | ((uint)l1 << 16);
      }
    }
    __syncthreads();
    f32x4 acc[2][2];  // [nrep][drep]
#pragma unroll
    for (int i = 0; i < 2; ++i)
#pragma unroll
      for (int j = 0; j < 2; ++j) acc[i][j] = (f32x4){0.f, 0.f, 0.f, 0.f};
#pragma unroll
    for (int wk = 0; wk < 2; ++wk) {
      int kk = wk * 32 + g * 8;
      bf16x8 xh[2], xl[2];
#pragma unroll
      for (int nr = 0; nr < 2; ++nr) {
        xh[nr] = ld8_b64(&Xth[nq * 32 + nr * 16 + fr][kk]);
        xl[nr] = ld8_b64(&Xtl[nq * 32 + nr * 16 + fr][kk]);
      }
#pragma unroll
      for (int nr = 0; nr < 2; ++nr)
#pragma unroll
        for (int dr = 0; dr < 2; ++dr) {
          acc[nr][dr] = mfma16(xh[nr], mh[dr][wk], acc[nr][dr]);
          acc[nr][dr] = mfma16(xh[nr], ml[dr][wk], acc[nr][dr]);
          acc[nr][dr] = mfma16(xl[nr], mh[dr][wk], acc[nr][dr]);
        }
    }
#pragma unroll
    for (int nr = 0; nr < 2; ++nr)
#pragma unroll
      for (int dr = 0; dr < 2; ++dr) {
        int d = dq * 32 + dr * 16 + fr;
        int n0 = nb + nq * 32 + nr * 16 + g * 4;
        f32x4 rx = nt_load4(Xr + (size_t)d * N_ + n0);
        float iv = invs[d], ad = adds[d], pb = pbs[d];
        float4 v;
        v.x = (acc[nr][dr][0] + pb + rx[0]) * iv + ad;
        v.y = (acc[nr][dr][1] + pb + rx[1]) * iv + ad;
        v.z = (acc[nr][dr][2] + pb + rx[2]) * iv + ad;
        v.w = (acc[nr][dr][3] + pb + rx[3]) * iv + ad;
        ushort4 o;
        o.x = f2bf(v.x); o.y = f2bf(v.y); o.z = f2bf(v.z); o.w = f2bf(v.w);
        *(ushort4*)(Y + (size_t)(d * 8 + h) * N_ + n0) = o;
      }
    __syncthreads();
  }
}

// ---------------- K46: MFMA Gram2 + stage-2 attention + PV + residual -> out ----------------
// grid 1024, block 256; gram = 2 independent MFMA chains (VGPR < 128).
// NT stores for `out` (never re-read) keep y resident in L2/L3.
__global__ __launch_bounds__(256) void k46_stage2(const ushort* __restrict__ y,
    const float* __restrict__ w2, const float* __restrict__ b2,
    float* __restrict__ out) {
  int orig = (blockIdx.x & 7) * 128 + (blockIdx.x >> 3);
  int b = orig >> 6, d = orig & 63;
  int gq = d / 3, gk = (64 + d) / 3, gv = (128 + d) / 3;
  int mq = d, mk = 64 + d, mv = 128 + d;
  int g2q = mq / 3, oq0 = (mq % 3) * 8;
  int g2k = mk / 3, ok0 = (mk % 3) * 8;
  int g2v = mv / 3, ov0 = (mv % 3) * 8;
  const ushort* Aq = y + ((size_t)b * 512 + gq * 8) * N_;
  const ushort* Ak = y + ((size_t)b * 512 + gk * 8) * N_;
  int t = threadIdx.x;
  int l = t & 63, w = t >> 6;

  __shared__ float W2q[8][8], W2k[8][8], W2v[8][8];
  __shared__ float bq2[8], bk2[8], bv2[8];
  __shared__ float red[4][16][16];
  __shared__ float gbuf[80];
  __shared__ float Ps[8][9];
  __shared__ float Msh[8][8], pbsh[8];
  if (t < 64) {
    int hh = t >> 3, ee = t & 7;
    W2q[hh][ee] = w2[(size_t)(g2q * 24 + oq0 + hh) * 8 + ee];
    W2k[hh][ee] = w2[(size_t)(g2k * 24 + ok0 + hh) * 8 + ee];
    W2v[hh][ee] = w2[(size_t)(g2v * 24 + ov0 + hh) * 8 + ee];
  }
  if (t < 8) {
    bq2[t] = b2[g2q * 24 + oq0 + t];
    bk2[t] = b2[g2k * 24 + ok0 + t];
    bv2[t] = b2[g2v * 24 + ov0 + t];
  }

  // ---- MFMA gram over relu(y), wave w covers n in [w*1024, w*1024+1024) ----
  // Gram trick: A-rows [q0..7,k0..7], B-cols [k0..7, ones, 0...] ->
  // C[0:8][0:8]=q.k^T, C[0:8][8]=sum q, C[8:16][8]=sum k.
  {
    int row16 = l & 15;
    int ko = (l >> 4) * 8;
    const ushort* Arow = (row16 < 8) ? (Aq + (size_t)row16 * N_)
                                     : (Ak + (size_t)(row16 - 8) * N_);
    const ushort* Brow = (row16 < 8) ? (Ak + (size_t)row16 * N_) : nullptr;
    ushort bv = (row16 == 8) ? (ushort)0x3F80 : (ushort)0;  // ones col / zero
    bf16x8 bconst = {(short)bv, (short)bv, (short)bv, (short)bv,
                     (short)bv, (short)bv, (short)bv, (short)bv};
    f32x4 accA = (f32x4){0.f, 0.f, 0.f, 0.f};
    f32x4 accB = (f32x4){0.f, 0.f, 0.f, 0.f};
    int nbase = w * 1024 + ko;
    __builtin_amdgcn_s_setprio(1);
#pragma unroll 4
    for (int step = 0; step < 16; ++step) {
      int n0 = nbase + step * 32;
      int n1 = n0 + 512;
      bf16x8 a0 = relu8(*(const bf16x8*)(Arow + n0));
      bf16x8 a1 = relu8(*(const bf16x8*)(Arow + n1));
      bf16x8 b0, b1;
      if (row16 < 8) {
        b0 = relu8(*(const bf16x8*)(Brow + n0));
        b1 = relu8(*(const bf16x8*)(Brow + n1));
      } else {
        b0 = bconst; b1 = bconst;
      }
      accA = mfma16(a0, b0, accA);
      accB = mfma16(a1, b1, accB);
    }
    __builtin_amdgcn_s_setprio(0);
    f32x4 acc;
#pragma unroll
    for (int r = 0; r < 4; ++r) acc[r] = accA[r] + accB[r];
    // C layout: col = l&15, row = (l>>4)*4 + reg
#pragma unroll
    for (int r = 0; r < 4; ++r) red[w][(l >> 4) * 4 + r][l & 15] = acc[r];
  }
  __syncthreads();
  {
    int rr = t >> 4, cc = t & 15;
    float csum = red[0][rr][cc] + red[1][rr][cc] + red[2][rr][cc] + red[3][rr][cc];
    if (rr < 8 && cc < 8) gbuf[rr * 8 + cc] = csum;
    else if (cc == 8) gbuf[rr < 8 ? 64 + rr : 72 + (rr - 8)] = csum;
  }
  __syncthreads();

  // ---- 8x8 attention algebra ----
  if (t < 64) {
    int hh = t >> 3, ee = t & 7;
    float s = 0.f;
#pragma unroll
    for (int i = 0; i < 8; ++i) {
      float pg = 0.f;
#pragma unroll
      for (int j = 0; j < 8; ++j) pg += gbuf[i * 8 + j] * W2k[ee][j];
      s += W2q[hh][i] * pg;
    }
    float dq = 0.f, dk = 0.f;
#pragma unroll
    for (int i = 0; i < 8; ++i) { dq += W2q[hh][i] * gbuf[64 + i]; dk += W2k[ee][i] * gbuf[72 + i]; }
    s = (s + bq2[hh] * dk + bk2[ee] * dq + 4096.f * bq2[hh] * bk2[ee]) * 0.35355339059327373f;
    s = ssqrt(s);
    float m = s;
#pragma unroll
    for (int mm = 1; mm < 8; mm <<= 1) m = fmaxf(m, __shfl_xor(m, mm));
    float p = expf(s - m);
    float sum = p;
#pragma unroll
    for (int mm = 1; mm < 8; mm <<= 1) sum += __shfl_xor(sum, mm);
    p /= sum;
    Ps[t >> 3][t & 7] = p;
  }
  __syncthreads();
  if (t < 64) {
    int hh = t >> 3, ee = t & 7;
    float mo = 0.f;
#pragma unroll
    for (int e = 0; e < 8; ++e) mo += Ps[hh][e] * W2v[e][ee];
    Msh[hh][ee] = mo;
  }
  if (t < 8) {
    float pb = 0.f;
#pragma unroll
    for (int e = 0; e < 8; ++e) pb += Ps[t][e] * bv2[e];
    pbsh[t] = pb;
  }
  __syncthreads();

  // ---- PV + residual -> out (NT stores) ----
  float msr[8][8], pbr[8];
#pragma unroll
  for (int hh = 0; hh < 8; ++hh) {
    pbr[hh] = pbsh[hh];
#pragma unroll
    for (int i = 0; i < 8; ++i) msr[hh][i] = Msh[hh][i];
  }
  const ushort* Yv = y + ((size_t)b * 512 + gv * 8) * N_;
  const ushort* Yr = y + ((size_t)b * 512 + d) * N_;
  float* O = out + ((size_t)b * 512 + d) * N_;
  for (int it = 0; it < 4; ++it) {
    int n4 = (it * 256 + t) * 4;
    float xv0[8], xv1[8], xv2[8], xv3[8];
#pragma unroll
    for (int i = 0; i < 8; ++i) {
      ushort4 u = *(const ushort4*)(Yv + (size_t)i * N_ + n4);
      xv0[i] = fmaxf(bf2f(u.x), 0.f); xv1[i] = fmaxf(bf2f(u.y), 0.f);
      xv2[i] = fmaxf(bf2f(u.z), 0.f); xv3[i] = fmaxf(bf2f(u.w), 0.f);
    }
#pragma unroll
    for (int hh = 0; hh < 8; ++hh) {
      float ax = pbr[hh], ay = pbr[hh], az = pbr[hh], aw = pbr[hh];
#pragma unroll
      for (int i = 0; i < 8; ++i) {
        float m = msr[hh][i];
        ax += m * xv0[i]; ay += m * xv1[i];
        az += m * xv2[i]; aw += m * xv3[i];
      }
      ushort4 r = *(const ushort4*)(Yr + (size_t)hh * 64 * N_ + n4);
      ax += bf2f(r.x); ay += bf2f(r.y); az += bf2f(r.z); aw += bf2f(r.w);
      nt_store4(O + (size_t)hh * 64 * N_ + n4, ax, ay, az, aw);
    }
  }
}

extern "C" void kernel_launch(void* const* d_in, const int* in_sizes, int n_in,
                              void* d_out, int out_size, void* d_ws, size_t ws_size,
                              hipStream_t stream) {
  const float* x     = (const float*)d_in[0];
  const float* w1    = (const float*)d_in[1];
  const float* b1    = (const float*)d_in[2];
  const float* w2    = (const float*)d_in[3];
  const float* b2    = (const float*)d_in[4];
  const float* gamma = (const float*)d_in[5];
  const float* beta  = (const float*)d_in[6];
  const float* rmean = (const float*)d_in[7];
  const float* rvar  = (const float*)d_in[8];
  float* out = (float*)d_out;

  // workspace layout
  ushort* y    = (ushort*)d_ws;              // 33,554,432 ushort (64 MiB)
  float* Gp    = (float*)(y + 33554432);     //  1,572,864 f (4s x 96 x 4096)
  float* sums  = Gp + 1572864;               //     24,576 f
  ushort* M1h  = (ushort*)(sums + 24576);    //    524,288 us
  ushort* M1l  = M1h + 524288;               //    524,288 us
  float* pbv1  = (float*)(M1l + 524288);     //      8,192 f
  size_t need = (size_t)67108864 + 6291456 + 98304 + 2097152 + 32768;
  if (ws_size < need) return;

  k1_gram<<<384, 256, 0, stream>>>(x, Gp, sums);
  k2_attn1<<<128, 256, 0, stream>>>(w1, b1, Gp, sums, M1h, M1l, pbv1);
  k3_out1<<<2048, 256, 0, stream>>>(x, M1h, M1l, pbv1, gamma, beta, rmean, rvar, y);
  k46_stage2<<<1024, 256, 0, stream>>>(y, w2, b2, out);
}

// Round 18
// 149.881 us; speedup vs baseline: 1.1188x; 1.1188x over previous
//
#include <hip/hip_runtime.h>

#define N_ 4096

typedef __attribute__((ext_vector_type(8))) short bf16x8;
typedef __attribute__((ext_vector_type(4))) short bf16x4;
typedef __attribute__((ext_vector_type(4))) float f32x4;

__device__ __forceinline__ float ssqrt(float a) {
  if (a == 0.f) return 0.f;
  return copysignf(sqrtf(fabsf(a) + 1e-5f), a);
}

__device__ __forceinline__ ushort f2bf(float f) {
  uint u = __float_as_uint(f);
  u += 0x7fff + ((u >> 16) & 1);  // RNE
  return (ushort)(u >> 16);
}
__device__ __forceinline__ float bf2f(ushort h) {
  return __uint_as_float((uint)h << 16);
}

// cheap truncation-based hi/lo split: hi+lo == f up to 2^-16 rel (lo truncated)
__device__ __forceinline__ void split2(float f, ushort& hi, ushort& lo) {
  uint u = __float_as_uint(f);
  hi = (ushort)(u >> 16);
  float lof = f - __uint_as_float(u & 0xffff0000u);
  lo = (ushort)(__float_as_uint(lof) >> 16);
}

__device__ __forceinline__ f32x4 mfma16(bf16x8 a, bf16x8 b, f32x4 c) {
  return __builtin_amdgcn_mfma_f32_16x16x32_bf16(a, b, c, 0, 0, 0);
}

// non-temporal float4 store (nt flag: bypass L2/L3 - data never re-read)
__device__ __forceinline__ void nt_store4(float* p, float x, float y, float z, float w) {
  f32x4 v = {x, y, z, w};
  __builtin_nontemporal_store(v, (f32x4*)p);
}

// packed relu on 8 bf16 (zero any half-word with sign bit set)
__device__ __forceinline__ bf16x8 relu8(bf16x8 v) {
  union { bf16x8 h; uint u[4]; } x;
  x.h = v;
#pragma unroll
  for (int i = 0; i < 4; ++i) {
    uint m = x.u[i] & 0x80008000u;
    x.u[i] &= ~((m >> 15) * 0xFFFFu);
  }
  return x.h;
}

// load 8 consecutive bf16 from an 8B-aligned LDS addr (2 x b64)
__device__ __forceinline__ bf16x8 ld8_b64(const ushort* p) {
  bf16x4 a = *(const bf16x4*)p;
  bf16x4 b = *(const bf16x4*)(p + 4);
  return (bf16x8){a[0], a[1], a[2], a[3], b[0], b[1], b[2], b[3]};
}

// ---------------- K1: Gram for stage 1 (MFMA bf16x3), 6 unique panel-pairs ----------------
__global__ __launch_bounds__(256) void k1_gram(const float* __restrict__ x,
    float* __restrict__ Gp, float* __restrict__ sums) {
  const int GQ[6] = {0, 0, 1, 1, 2, 2};
  const int GK[6] = {2, 3, 3, 4, 4, 5};
  int bid = (blockIdx.x & 7) * 48 + (blockIdx.x >> 3);
  int s = bid / 96, rem = bid % 96;
  int b = rem / 6, pid = rem % 6;
  int gq = GQ[pid], gk = GK[pid];
  const float* A = x + ((size_t)b * 512 + gq * 64) * N_ + s * 1024;
  const float* B = x + ((size_t)b * 512 + gk * 64) * N_ + s * 1024;
  __shared__ __attribute__((aligned(16))) ushort Ah[64][72], Al[64][72];
  __shared__ __attribute__((aligned(16))) ushort Bh[64][72], Bl[64][72];
  int t = threadIdx.x;
  int lr = t >> 2, lq = t & 3;
  int l = t & 63, w = t >> 6;
  int mw = (w >> 1) * 32, nw = (w & 1) * 32;
  int fr = l & 15, ko = (l >> 4) * 8;
  float sumA = 0.f, sumB = 0.f;
  f32x4 acc[2][2];
#pragma unroll
  for (int i = 0; i < 2; ++i)
#pragma unroll
    for (int j = 0; j < 2; ++j) acc[i][j] = (f32x4){0.f, 0.f, 0.f, 0.f};

  for (int kt = 0; kt < 16; ++kt) {
    int kbase = kt * 64 + lq * 16;
#pragma unroll
    for (int j = 0; j < 4; ++j) {
      float4 va = *(const float4*)(A + (size_t)lr * N_ + kbase + j * 4);
      float4 vb = *(const float4*)(B + (size_t)lr * N_ + kbase + j * 4);
      sumA += va.x + va.y + va.z + va.w;
      sumB += vb.x + vb.y + vb.z + vb.w;
      ushort4 ha, la, hb, lb;
      split2(va.x, ha.x, la.x); split2(va.y, ha.y, la.y);
      split2(va.z, ha.z, la.z); split2(va.w, ha.w, la.w);
      split2(vb.x, hb.x, lb.x); split2(vb.y, hb.y, lb.y);
      split2(vb.z, hb.z, lb.z); split2(vb.w, hb.w, lb.w);
      int c0 = lq * 16 + j * 4;
      *(ushort4*)&Ah[lr][c0] = ha;
      *(ushort4*)&Al[lr][c0] = la;
      *(ushort4*)&Bh[lr][c0] = hb;
      *(ushort4*)&Bl[lr][c0] = lb;
    }
    __syncthreads();
#pragma unroll
    for (int wk = 0; wk < 2; ++wk) {
      int kk = wk * 32 + ko;
      bf16x8 ah[2], al[2], bh[2], bl[2];
#pragma unroll
      for (int mt = 0; mt < 2; ++mt) {
        ah[mt] = *(const bf16x8*)&Ah[mw + mt * 16 + fr][kk];
        al[mt] = *(const bf16x8*)&Al[mw + mt * 16 + fr][kk];
      }
#pragma unroll
      for (int nt = 0; nt < 2; ++nt) {
        bh[nt] = *(const bf16x8*)&Bh[nw + nt * 16 + fr][kk];
        bl[nt] = *(const bf16x8*)&Bl[nw + nt * 16 + fr][kk];
      }
#pragma unroll
      for (int mt = 0; mt < 2; ++mt)
#pragma unroll
        for (int nt = 0; nt < 2; ++nt) {
          acc[mt][nt] = mfma16(ah[mt], bh[nt], acc[mt][nt]);
          acc[mt][nt] = mfma16(ah[mt], bl[nt], acc[mt][nt]);
          acc[mt][nt] = mfma16(al[mt], bh[nt], acc[mt][nt]);
        }
    }
    __syncthreads();
  }
  size_t base = ((size_t)s * 96 + rem) * 4096;
#pragma unroll
  for (int mt = 0; mt < 2; ++mt)
#pragma unroll
    for (int nt = 0; nt < 2; ++nt)
#pragma unroll
      for (int reg = 0; reg < 4; ++reg) {
        int gr = mw + mt * 16 + (l >> 4) * 4 + reg;
        int gc = nw + nt * 16 + fr;
        __builtin_nontemporal_store(acc[mt][nt][reg],
                                    &Gp[base + (size_t)gr * 64 + gc]);
      }
  sumA += __shfl_xor(sumA, 1); sumA += __shfl_xor(sumA, 2);
  sumB += __shfl_xor(sumB, 1); sumB += __shfl_xor(sumB, 2);
  if (lq == 0) {
    sums[(((size_t)s * 16 + b) * 6 + gq) * 64 + lr] = sumA;
    sums[(((size_t)s * 16 + b) * 6 + gk) * 64 + lr] = sumB;
  }
}

// ---------------- K2: per-(b,h) attention algebra ----------------
__global__ __launch_bounds__(256) void k2_attn1(
    const float* __restrict__ w1, const float* __restrict__ b1,
    const float* __restrict__ Gp, const float* __restrict__ sums,
    ushort* __restrict__ M1h, ushort* __restrict__ M1l,
    float* __restrict__ pbv1) {
  const int PID[8] = {0, 1, 1, 2, 3, 3, 4, 5};
  int bh = blockIdx.x;
  int b = bh >> 3, h = bh & 7;
  int pid = PID[h];
  int mq = h, mk = 8 + h, mv = 16 + h;
  int gq = mq / 3, oq0 = (mq % 3) * 64;
  int gk = mk / 3, ok0 = (mk % 3) * 64;
  int gv = mv / 3, ov0 = (mv % 3) * 64;
  __shared__ __attribute__((aligned(16))) float Gs[64][68];
  __shared__ __attribute__((aligned(16))) float Was[64][68];
  __shared__ __attribute__((aligned(16))) float Wbs[64][68];
  __shared__ __attribute__((aligned(16))) float Ts[64][68];
  __shared__ float sxs[64], sks[64], vqs[64], vks[64], bvs[64];
  int t = threadIdx.x, tx = t & 15, ty = t >> 4;
  int d0 = ty * 4, e0 = tx * 4;

  for (int f = t; f < 4096; f += 256) {
    int dd = f >> 6, ee = f & 63;
    float g = 0.f;
#pragma unroll
    for (int s = 0; s < 4; ++s)
      g += Gp[((size_t)s * 96 + b * 6 + pid) * 4096 + f];
    Gs[dd][ee] = g;
    Was[dd][ee] = w1[((size_t)(gq * 192 + oq0 + dd)) * 64 + ee];
    Wbs[dd][ee] = w1[((size_t)(gk * 192 + ok0 + dd)) * 64 + ee];
  }
  if (t < 64) {
    float v = 0.f, w = 0.f;
#pragma unroll
    for (int s = 0; s < 4; ++s) {
      v += sums[(((size_t)s * 16 + b) * 6 + gq) * 64 + t];
      w += sums[(((size_t)s * 16 + b) * 6 + gk) * 64 + t];
    }
    sxs[t] = v; sks[t] = w;
    bvs[t] = b1[gv * 192 + ov0 + t];
  }
  __syncthreads();
  if (t < 64) {
    float vq = 0.f, vk = 0.f;
    for (int i = 0; i < 64; ++i) { vq += Was[t][i] * sxs[i]; vk += Wbs[t][i] * sks[i]; }
    vqs[t] = vq; vks[t] = vk;
  }
  {
    float acc[4][4] = {};
    for (int i = 0; i < 64; i += 4) {
      float4 a4[4], g4[4];
#pragma unroll
      for (int r = 0; r < 4; ++r) a4[r] = *(const float4*)&Was[d0 + r][i];
#pragma unroll
      for (int k = 0; k < 4; ++k) g4[k] = *(const float4*)&Gs[i + k][e0];
#pragma unroll
      for (int r = 0; r < 4; ++r) {
        const float* ap = (const float*)&a4[r];
#pragma unroll
        for (int k = 0; k < 4; ++k) {
          const float* gp = (const float*)&g4[k];
#pragma unroll
          for (int c = 0; c < 4; ++c) acc[r][c] += ap[k] * gp[c];
        }
      }
    }
#pragma unroll
    for (int r = 0; r < 4; ++r)
#pragma unroll
      for (int c = 0; c < 4; ++c) Ts[d0 + r][e0 + c] = acc[r][c];
  }
  __syncthreads();
  float P[4][4];
  {
    float s[4][4] = {};
    for (int j = 0; j < 64; j += 4) {
      float4 t4[4], w4[4];
#pragma unroll
      for (int r = 0; r < 4; ++r) t4[r] = *(const float4*)&Ts[d0 + r][j];
#pragma unroll
      for (int c = 0; c < 4; ++c) w4[c] = *(const float4*)&Wbs[e0 + c][j];
#pragma unroll
      for (int r = 0; r < 4; ++r)
#pragma unroll
        for (int c = 0; c < 4; ++c)
          s[r][c] += t4[r].x * w4[c].x + t4[r].y * w4[c].y
                   + t4[r].z * w4[c].z + t4[r].w * w4[c].w;
    }
    float bq_[4], bk_[4];
#pragma unroll
    for (int r = 0; r < 4; ++r) bq_[r] = b1[gq * 192 + oq0 + d0 + r];
#pragma unroll
    for (int c = 0; c < 4; ++c) bk_[c] = b1[gk * 192 + ok0 + e0 + c];
#pragma unroll
    for (int r = 0; r < 4; ++r)
#pragma unroll
      for (int c = 0; c < 4; ++c) {
        float v = (s[r][c] + bq_[r] * vks[e0 + c] + bk_[c] * vqs[d0 + r]
                   + 4096.f * bq_[r] * bk_[c]) * 0.125f;
        s[r][c] = ssqrt(v);
      }
#pragma unroll
    for (int r = 0; r < 4; ++r) {
      float m = fmaxf(fmaxf(s[r][0], s[r][1]), fmaxf(s[r][2], s[r][3]));
#pragma unroll
      for (int mm = 1; mm < 16; mm <<= 1) m = fmaxf(m, __shfl_xor(m, mm));
      float sum = 0.f;
#pragma unroll
      for (int c = 0; c < 4; ++c) { s[r][c] = expf(s[r][c] - m); sum += s[r][c]; }
#pragma unroll
      for (int mm = 1; mm < 16; mm <<= 1) sum += __shfl_xor(sum, mm);
      float inv = 1.f / sum;
#pragma unroll
      for (int c = 0; c < 4; ++c) P[r][c] = s[r][c] * inv;
    }
  }
#pragma unroll
  for (int r = 0; r < 4; ++r)
#pragma unroll
    for (int c = 0; c < 4; ++c) Gs[d0 + r][e0 + c] = P[r][c];
  for (int f = t; f < 4096; f += 256) {
    int ee = f >> 6, ii = f & 63;
    Was[ee][ii] = w1[((size_t)(gv * 192 + ov0 + ee)) * 64 + ii];
  }
  __syncthreads();
  {
    float acc[4][4] = {};
    for (int e = 0; e < 64; e += 4) {
      float4 p4[4], v4[4];
#pragma unroll
      for (int r = 0; r < 4; ++r) p4[r] = *(const float4*)&Gs[d0 + r][e];
#pragma unroll
      for (int k = 0; k < 4; ++k) v4[k] = *(const float4*)&Was[e + k][e0];
#pragma unroll
      for (int r = 0; r < 4; ++r) {
        const float* pp = (const float*)&p4[r];
#pragma unroll
        for (int k = 0; k < 4; ++k) {
          const float* vp = (const float*)&v4[k];
#pragma unroll
          for (int c = 0; c < 4; ++c) acc[r][c] += pp[k] * vp[c];
        }
      }
    }
    ushort* MoH = M1h + (size_t)bh * 4096;
    ushort* MoL = M1l + (size_t)bh * 4096;
#pragma unroll
    for (int r = 0; r < 4; ++r)
#pragma unroll
      for (int c = 0; c < 4; ++c) {
        float vv = acc[r][c];
        ushort hi = f2bf(vv);
        MoH[(size_t)(d0 + r) * 64 + e0 + c] = hi;
        MoL[(size_t)(d0 + r) * 64 + e0 + c] = f2bf(vv - bf2f(hi));
      }
  }
  if (t < 64) {
    float pb = 0.f;
    for (int e = 0; e < 64; ++e) pb += Gs[t][e] * bvs[e];
    pbv1[(size_t)bh * 64 + t] = pb;
  }
}

// ---------------- K3: outT = XvT @ M^T via MFMA; +pbv+res, BN, permute -> y (bf16) ----------------
__global__ __launch_bounds__(256) void k3_out1(const float* __restrict__ x,
    const ushort* __restrict__ M1h, const ushort* __restrict__ M1l,
    const float* __restrict__ pbv1,
    const float* __restrict__ gamma, const float* __restrict__ beta,
    const float* __restrict__ rmean, const float* __restrict__ rvar,
    ushort* __restrict__ y) {
  int orig = (blockIdx.x & 7) * 256 + (blockIdx.x >> 3);
  int b = orig >> 7;
  int rem = orig & 127;
  int chunk = rem >> 3, h = rem & 7;
  int bh = b * 8 + h;
  int gv = (16 + h) / 3;
  const float* Xv = x + ((size_t)b * 512 + gv * 64) * N_ + chunk * 256;
  const float* Xr = x + ((size_t)b * 512 + h * 64) * N_ + chunk * 256;
  ushort* Y = y + (size_t)b * 512 * N_ + chunk * 256;

  __shared__ __attribute__((aligned(16))) ushort Xth[64][68], Xtl[64][68];  // [n][e]
  __shared__ float pbs[64], invs[64], adds[64];
  int t = threadIdx.x;
  if (t < 64) {
    pbs[t] = pbv1[(size_t)bh * 64 + t];
    int c = t * 8 + h;
    float iv = gamma[c] / sqrtf(rvar[c] + 1e-5f);
    invs[t] = iv;
    adds[t] = beta[c] - rmean[c] * iv;
  }
  int l = t & 63, w = t >> 6;
  int dq = w >> 1, nq = w & 1;   // wave quadrant: 32d x 32n
  int fr = l & 15, g = l >> 4;

  bf16x8 mh[2][2], ml[2][2];  // [drep][wk]
  {
    const ushort* MbH = M1h + (size_t)bh * 4096;
    const ushort* MbL = M1l + (size_t)bh * 4096;
#pragma unroll
    for (int dr = 0; dr < 2; ++dr)
#pragma unroll
      for (int wk = 0; wk < 2; ++wk) {
        int off = (dq * 32 + dr * 16 + fr) * 64 + wk * 32 + g * 8;
        mh[dr][wk] = *(const bf16x8*)(MbH + off);
        ml[dr][wk] = *(const bf16x8*)(MbL + off);
      }
  }

  int e2 = t >> 3, q = t & 7;
  for (int tile = 0; tile < 4; ++tile) {
    int nb = tile * 64;
    {
      const float* r0p = Xv + (size_t)(2 * e2) * N_ + nb + q * 8;
      const float* r1p = r0p + N_;
      float4 a0 = *(const float4*)r0p, a1 = *(const float4*)(r0p + 4);
      float4 b0 = *(const float4*)r1p, b1 = *(const float4*)(r1p + 4);
      float ra[8] = {a0.x, a0.y, a0.z, a0.w, a1.x, a1.y, a1.z, a1.w};
      float rb[8] = {b0.x, b0.y, b0.z, b0.w, b1.x, b1.y, b1.z, b1.w};
#pragma unroll
      for (int i = 0; i < 8; ++i) {
        int n = q * 8 + i;
        ushort h0, l0, h1, l1;
        split2(ra[i], h0, l0);
        split2(rb[i], h1, l1);
        *(uint*)&Xth[n][2 * e2] = (uint)h0 | ((uint)h1 << 16);
        *(uint*)&Xtl[n][2 * e2] = (uint)l0 | ((uint)l1 << 16);
      }
    }
    __syncthreads();
    f32x4 acc[2][2];  // [nrep][drep]
#pragma unroll
    for (int i = 0; i < 2; ++i)
#pragma unroll
      for (int j = 0; j < 2; ++j) acc[i][j] = (f32x4){0.f, 0.f, 0.f, 0.f};
#pragma unroll
    for (int wk = 0; wk < 2; ++wk) {
      int kk = wk * 32 + g * 8;
      bf16x8 xh[2], xl[2];
#pragma unroll
      for (int nr = 0; nr < 2; ++nr) {
        xh[nr] = ld8_b64(&Xth[nq * 32 + nr * 16 + fr][kk]);
        xl[nr] = ld8_b64(&Xtl[nq * 32 + nr * 16 + fr][kk]);
      }
#pragma unroll
      for (int nr = 0; nr < 2; ++nr)
#pragma unroll
        for (int dr = 0; dr < 2; ++dr) {
          acc[nr][dr] = mfma16(xh[nr], mh[dr][wk], acc[nr][dr]);
          acc[nr][dr] = mfma16(xh[nr], ml[dr][wk], acc[nr][dr]);
          acc[nr][dr] = mfma16(xl[nr], mh[dr][wk], acc[nr][dr]);
        }
    }
#pragma unroll
    for (int nr = 0; nr < 2; ++nr)
#pragma unroll
      for (int dr = 0; dr < 2; ++dr) {
        int d = dq * 32 + dr * 16 + fr;
        int n0 = nb + nq * 32 + nr * 16 + g * 4;
        float4 rx = *(const float4*)(Xr + (size_t)d * N_ + n0);
        float iv = invs[d], ad = adds[d], pb = pbs[d];
        float4 v;
        v.x = (acc[nr][dr][0] + pb + rx.x) * iv + ad;
        v.y = (acc[nr][dr][1] + pb + rx.y) * iv + ad;
        v.z = (acc[nr][dr][2] + pb + rx.z) * iv + ad;
        v.w = (acc[nr][dr][3] + pb + rx.w) * iv + ad;
        ushort4 o;
        o.x = f2bf(v.x); o.y = f2bf(v.y); o.z = f2bf(v.z); o.w = f2bf(v.w);
        *(ushort4*)(Y + (size_t)(d * 8 + h) * N_ + n0) = o;
      }
    __syncthreads();
  }
}

// ---------------- K46: MFMA Gram2 + stage-2 attention + PV + residual -> out ----------------
// grid 1024, block 256; gram = 2 independent MFMA chains (VGPR < 128).
// NT stores for `out` (never re-read) keep y resident in L2/L3.
__global__ __launch_bounds__(256) void k46_stage2(const ushort* __restrict__ y,
    const float* __restrict__ w2, const float* __restrict__ b2,
    float* __restrict__ out) {
  int orig = (blockIdx.x & 7) * 128 + (blockIdx.x >> 3);
  int b = orig >> 6, d = orig & 63;
  int gq = d / 3, gk = (64 + d) / 3, gv = (128 + d) / 3;
  int mq = d, mk = 64 + d, mv = 128 + d;
  int g2q = mq / 3, oq0 = (mq % 3) * 8;
  int g2k = mk / 3, ok0 = (mk % 3) * 8;
  int g2v = mv / 3, ov0 = (mv % 3) * 8;
  const ushort* Aq = y + ((size_t)b * 512 + gq * 8) * N_;
  const ushort* Ak = y + ((size_t)b * 512 + gk * 8) * N_;
  int t = threadIdx.x;
  int l = t & 63, w = t >> 6;

  __shared__ float W2q[8][8], W2k[8][8], W2v[8][8];
  __shared__ float bq2[8], bk2[8], bv2[8];
  __shared__ float red[4][16][16];
  __shared__ float gbuf[80];
  __shared__ float Ps[8][9];
  __shared__ float Msh[8][8], pbsh[8];
  if (t < 64) {
    int hh = t >> 3, ee = t & 7;
    W2q[hh][ee] = w2[(size_t)(g2q * 24 + oq0 + hh) * 8 + ee];
    W2k[hh][ee] = w2[(size_t)(g2k * 24 + ok0 + hh) * 8 + ee];
    W2v[hh][ee] = w2[(size_t)(g2v * 24 + ov0 + hh) * 8 + ee];
  }
  if (t < 8) {
    bq2[t] = b2[g2q * 24 + oq0 + t];
    bk2[t] = b2[g2k * 24 + ok0 + t];
    bv2[t] = b2[g2v * 24 + ov0 + t];
  }

  // ---- MFMA gram over relu(y), wave w covers n in [w*1024, w*1024+1024) ----
  // Gram trick: A-rows [q0..7,k0..7], B-cols [k0..7, ones, 0...] ->
  // C[0:8][0:8]=q.k^T, C[0:8][8]=sum q, C[8:16][8]=sum k.
  {
    int row16 = l & 15;
    int ko = (l >> 4) * 8;
    const ushort* Arow = (row16 < 8) ? (Aq + (size_t)row16 * N_)
                                     : (Ak + (size_t)(row16 - 8) * N_);
    const ushort* Brow = (row16 < 8) ? (Ak + (size_t)row16 * N_) : nullptr;
    ushort bv = (row16 == 8) ? (ushort)0x3F80 : (ushort)0;  // ones col / zero
    bf16x8 bconst = {(short)bv, (short)bv, (short)bv, (short)bv,
                     (short)bv, (short)bv, (short)bv, (short)bv};
    f32x4 accA = (f32x4){0.f, 0.f, 0.f, 0.f};
    f32x4 accB = (f32x4){0.f, 0.f, 0.f, 0.f};
    int nbase = w * 1024 + ko;
    __builtin_amdgcn_s_setprio(1);
#pragma unroll 4
    for (int step = 0; step < 16; ++step) {
      int n0 = nbase + step * 32;
      int n1 = n0 + 512;
      bf16x8 a0 = relu8(*(const bf16x8*)(Arow + n0));
      bf16x8 a1 = relu8(*(const bf16x8*)(Arow + n1));
      bf16x8 b0, b1;
      if (row16 < 8) {
        b0 = relu8(*(const bf16x8*)(Brow + n0));
        b1 = relu8(*(const bf16x8*)(Brow + n1));
      } else {
        b0 = bconst; b1 = bconst;
      }
      accA = mfma16(a0, b0, accA);
      accB = mfma16(a1, b1, accB);
    }
    __builtin_amdgcn_s_setprio(0);
    f32x4 acc;
#pragma unroll
    for (int r = 0; r < 4; ++r) acc[r] = accA[r] + accB[r];
    // C layout: col = l&15, row = (l>>4)*4 + reg
#pragma unroll
    for (int r = 0; r < 4; ++r) red[w][(l >> 4) * 4 + r][l & 15] = acc[r];
  }
  __syncthreads();
  {
    int rr = t >> 4, cc = t & 15;
    float csum = red[0][rr][cc] + red[1][rr][cc] + red[2][rr][cc] + red[3][rr][cc];
    if (rr < 8 && cc < 8) gbuf[rr * 8 + cc] = csum;
    else if (cc == 8) gbuf[rr < 8 ? 64 + rr : 72 + (rr - 8)] = csum;
  }
  __syncthreads();

  // ---- 8x8 attention algebra ----
  if (t < 64) {
    int hh = t >> 3, ee = t & 7;
    float s = 0.f;
#pragma unroll
    for (int i = 0; i < 8; ++i) {
      float pg = 0.f;
#pragma unroll
      for (int j = 0; j < 8; ++j) pg += gbuf[i * 8 + j] * W2k[ee][j];
      s += W2q[hh][i] * pg;
    }
    float dq = 0.f, dk = 0.f;
#pragma unroll
    for (int i = 0; i < 8; ++i) { dq += W2q[hh][i] * gbuf[64 + i]; dk += W2k[ee][i] * gbuf[72 + i]; }
    s = (s + bq2[hh] * dk + bk2[ee] * dq + 4096.f * bq2[hh] * bk2[ee]) * 0.35355339059327373f;
    s = ssqrt(s);
    float m = s;
#pragma unroll
    for (int mm = 1; mm < 8; mm <<= 1) m = fmaxf(m, __shfl_xor(m, mm));
    float p = expf(s - m);
    float sum = p;
#pragma unroll
    for (int mm = 1; mm < 8; mm <<= 1) sum += __shfl_xor(sum, mm);
    p /= sum;
    Ps[t >> 3][t & 7] = p;
  }
  __syncthreads();
  if (t < 64) {
    int hh = t >> 3, ee = t & 7;
    float mo = 0.f;
#pragma unroll
    for (int e = 0; e < 8; ++e) mo += Ps[hh][e] * W2v[e][ee];
    Msh[hh][ee] = mo;
  }
  if (t < 8) {
    float pb = 0.f;
#pragma unroll
    for (int e = 0; e < 8; ++e) pb += Ps[t][e] * bv2[e];
    pbsh[t] = pb;
  }
  __syncthreads();

  // ---- PV + residual -> out (NT stores) ----
  float msr[8][8], pbr[8];
#pragma unroll
  for (int hh = 0; hh < 8; ++hh) {
    pbr[hh] = pbsh[hh];
#pragma unroll
    for (int i = 0; i < 8; ++i) msr[hh][i] = Msh[hh][i];
  }
  const ushort* Yv = y + ((size_t)b * 512 + gv * 8) * N_;
  const ushort* Yr = y + ((size_t)b * 512 + d) * N_;
  float* O = out + ((size_t)b * 512 + d) * N_;
  for (int it = 0; it < 4; ++it) {
    int n4 = (it * 256 + t) * 4;
    float xv0[8], xv1[8], xv2[8], xv3[8];
#pragma unroll
    for (int i = 0; i < 8; ++i) {
      ushort4 u = *(const ushort4*)(Yv + (size_t)i * N_ + n4);
      xv0[i] = fmaxf(bf2f(u.x), 0.f); xv1[i] = fmaxf(bf2f(u.y), 0.f);
      xv2[i] = fmaxf(bf2f(u.z), 0.f); xv3[i] = fmaxf(bf2f(u.w), 0.f);
    }
#pragma unroll
    for (int hh = 0; hh < 8; ++hh) {
      float ax = pbr[hh], ay = pbr[hh], az = pbr[hh], aw = pbr[hh];
#pragma unroll
      for (int i = 0; i < 8; ++i) {
        float m = msr[hh][i];
        ax += m * xv0[i]; ay += m * xv1[i];
        az += m * xv2[i]; aw += m * xv3[i];
      }
      ushort4 r = *(const ushort4*)(Yr + (size_t)hh * 64 * N_ + n4);
      ax += bf2f(r.x); ay += bf2f(r.y); az += bf2f(r.z); aw += bf2f(r.w);
      nt_store4(O + (size_t)hh * 64 * N_ + n4, ax, ay, az, aw);
    }
  }
}

extern "C" void kernel_launch(void* const* d_in, const int* in_sizes, int n_in,
                              void* d_out, int out_size, void* d_ws, size_t ws_size,
                              hipStream_t stream) {
  const float* x     = (const float*)d_in[0];
  const float* w1    = (const float*)d_in[1];
  const float* b1    = (const float*)d_in[2];
  const float* w2    = (const float*)d_in[3];
  const float* b2    = (const float*)d_in[4];
  const float* gamma = (const float*)d_in[5];
  const float* beta  = (const float*)d_in[6];
  const float* rmean = (const float*)d_in[7];
  const float* rvar  = (const float*)d_in[8];
  float* out = (float*)d_out;

  // workspace layout
  ushort* y    = (ushort*)d_ws;              // 33,554,432 ushort (64 MiB)
  float* Gp    = (float*)(y + 33554432);     //  1,572,864 f (4s x 96 x 4096)
  float* sums  = Gp + 1572864;               //     24,576 f
  ushort* M1h  = (ushort*)(sums + 24576);    //    524,288 us
  ushort* M1l  = M1h + 524288;               //    524,288 us
  float* pbv1  = (float*)(M1l + 524288);     //      8,192 f
  size_t need = (size_t)67108864 + 6291456 + 98304 + 2097152 + 32768;
  if (ws_size < need) return;

  k1_gram<<<384, 256, 0, stream>>>(x, Gp, sums);
  k2_attn1<<<128, 256, 0, stream>>>(w1, b1, Gp, sums, M1h, M1l, pbv1);
  k3_out1<<<2048, 256, 0, stream>>>(x, M1h, M1l, pbv1, gamma, beta, rmean, rvar, y);
  k46_stage2<<<1024, 256, 0, stream>>>(y, w2, b2, out);
}